// Round 20
// baseline (100.428 us; speedup 1.0000x reference)
//
#include <hip/hip_runtime.h>
#include <hip/hip_bf16.h>
#include <cstdint>

#define N_NODES 8192
#define F_IN    512
#define D_O     64
#define H_N     8
#define NOUT    512   // H_N * D_O
#define MAXD    128   // max supported degree (mean ~33.8, sigma 5.7 -> 16 sigma)

#define BM 64
#define BN 128
#define BK 64

typedef __attribute__((ext_vector_type(8))) short short8;
typedef __attribute__((ext_vector_type(4))) float f32x4;
typedef __attribute__((ext_vector_type(2))) float f32x2;
typedef __attribute__((ext_vector_type(4))) unsigned int uintv4;

static __device__ __forceinline__ ushort f2bf(float f) {
  union { float f; uint32_t u; } v; v.f = f;
  uint32_t r = v.u + 0x7FFFu + ((v.u >> 16) & 1u);  // RNE
  return (ushort)(r >> 16);
}
static __device__ __forceinline__ float bf2f(ushort u) {
  union { uint32_t u; float f; } v; v.u = ((uint32_t)u) << 16;
  return v.f;
}

// ---------------------------------------------------------------------------
// Kernel 0: blocks [0,2048): xb = bf16(x)   (grid-stride float4)
//           blocks [2048,2112): Wt[h][d][k] = bf16(W[h][k][d]) via LDS tile
// ---------------------------------------------------------------------------
__global__ __launch_bounds__(256) void convert(const float* __restrict__ x,
                                               const float* __restrict__ W,
                                               ushort* __restrict__ xb,
                                               ushort* __restrict__ Wt) {
  __shared__ float Ws[64][65];
  const int b = blockIdx.x, t = threadIdx.x;
  if (b < 2048) {
    const int gid = b * 256 + t;
    #pragma unroll
    for (int it = 0; it < 2; ++it) {
      const int q = gid + it * 524288;           // 2*524288 = 1,048,576 float4s
      const float4 v = ((const float4*)x)[q];
      ushort4 u;
      u.x = f2bf(v.x); u.y = f2bf(v.y); u.z = f2bf(v.z); u.w = f2bf(v.w);
      ((ushort4*)xb)[q] = u;
    }
  } else {
    const int bb = b - 2048;                     // 64 blocks = 8 heads x 8 k-tiles
    const int h = bb >> 3, kt = bb & 7;
    const int d = t & 63, krg = (t >> 6) * 16;
    const float* src = &W[((size_t)h * F_IN + kt * 64 + krg) * D_O + d];
    #pragma unroll
    for (int q = 0; q < 16; ++q)
      Ws[krg + q][d] = src[(size_t)q * D_O];     // coalesced over d
    __syncthreads();
    const int d0 = t >> 2, kq = (t & 3) * 16;
    ushort* dst = &Wt[(size_t)h * D_O * F_IN + (size_t)d0 * F_IN + kt * 64 + kq];
    #pragma unroll
    for (int q = 0; q < 16; ++q)
      dst[q] = f2bf(Ws[kq + q][d0]);             // coalesced over k
  }
}

// ---------------------------------------------------------------------------
// Kernel 1 (fused): blocks [0,512): GEMM tiles; blocks [512,8704): adj-row
// scan writing ushort CSR (nt adj loads). R11-verbatim.
// ---------------------------------------------------------------------------
__global__ __launch_bounds__(256) void scan_gemm(const uint32_t* __restrict__ adj,
                                                 const ushort* __restrict__ xb,
                                                 const ushort* __restrict__ Wt,
                                                 const float* __restrict__ a1,
                                                 const float* __restrict__ a2,
                                                 ushort* __restrict__ Whb,
                                                 float* __restrict__ f1,
                                                 float* __restrict__ f2,
                                                 ushort* __restrict__ nbr_g,
                                                 int* __restrict__ deg_g) {
  __shared__ ushort As[BM][BK + 8];
  __shared__ ushort Bs[BN][BK + 8];
  __shared__ int wsum[4];

  const int id   = blockIdx.x;
  const int tid  = threadIdx.x;
  const int lane = tid & 63;
  const int wv   = tid >> 6;

  if (id < 512) {
    // ---------------- GEMM role ----------------
    const int wr = wv >> 1, wc = wv & 1;
    const int r0 = (id >> 2) * BM;
    const int c0 = (id & 3) * BN;
    const int lm = lane & 15;
    const int lg = lane >> 4;

    f32x4 acc[2][4];
    #pragma unroll
    for (int m2 = 0; m2 < 2; ++m2)
      #pragma unroll
      for (int n2 = 0; n2 < 4; ++n2)
        acc[m2][n2] = (f32x4){0.f, 0.f, 0.f, 0.f};

    for (int k0 = 0; k0 < F_IN; k0 += BK) {
      __syncthreads();
      #pragma unroll
      for (int p = 0; p < 2; ++p) {
        const int e = p * 256 + tid;
        const int row = e >> 3, ck = (e & 7) * 8;
        *(short8*)&As[row][ck] = *(const short8*)&xb[(size_t)(r0 + row) * F_IN + k0 + ck];
      }
      #pragma unroll
      for (int p = 0; p < 4; ++p) {
        const int e = p * 256 + tid;
        const int row = e >> 3, ck = (e & 7) * 8;
        *(short8*)&Bs[row][ck] = *(const short8*)&Wt[(size_t)(c0 + row) * F_IN + k0 + ck];
      }
      __syncthreads();

      #pragma unroll
      for (int kk = 0; kk < 2; ++kk) {
        const int koff = kk * 32 + lg * 8;
        short8 af[2], bf[4];
        #pragma unroll
        for (int m2 = 0; m2 < 2; ++m2)
          af[m2] = *(const short8*)&As[wr * 32 + m2 * 16 + lm][koff];
        #pragma unroll
        for (int n2 = 0; n2 < 4; ++n2)
          bf[n2] = *(const short8*)&Bs[wc * 64 + n2 * 16 + lm][koff];
        #pragma unroll
        for (int m2 = 0; m2 < 2; ++m2)
          #pragma unroll
          for (int n2 = 0; n2 < 4; ++n2)
            acc[m2][n2] = __builtin_amdgcn_mfma_f32_16x16x32_bf16(af[m2], bf[n2], acc[m2][n2], 0, 0, 0);
      }
    }

    // epilogue: Whb write + fused f1/f2
    const int head = (c0 >> 6) + wc;
    float a1v[4], a2v[4];
    #pragma unroll
    for (int n2 = 0; n2 < 4; ++n2) {
      a1v[n2] = a1[head * D_O + n2 * 16 + lm];
      a2v[n2] = a2[head * D_O + n2 * 16 + lm];
    }
    #pragma unroll
    for (int m2 = 0; m2 < 2; ++m2) {
      #pragma unroll
      for (int r = 0; r < 4; ++r) {
        const int row = r0 + wr * 32 + m2 * 16 + lg * 4 + r;
        float p1 = 0.f, p2 = 0.f;
        #pragma unroll
        for (int n2 = 0; n2 < 4; ++n2) {
          const float v = acc[m2][n2][r];
          p1 += v * a1v[n2];
          p2 += v * a2v[n2];
          Whb[(size_t)row * NOUT + c0 + wc * 64 + n2 * 16 + lm] = f2bf(v);
        }
        #pragma unroll
        for (int o = 1; o < 16; o <<= 1) {
          p1 += __shfl_xor(p1, o);
          p2 += __shfl_xor(p2, o);
        }
        if (lm == 0) {
          f1[(size_t)row * H_N + head] = p1;
          f2[(size_t)row * H_N + head] = p2;
        }
      }
    }
  } else {
    // ---------------- SCAN role (nt loads) ----------------
    const int i = id - 512;
    const uint32_t* arow = adj + (size_t)i * N_NODES;
    uint32_t bits = 0;
    #pragma unroll
    for (int u = 0; u < 8; ++u) {
      const uintv4 a = __builtin_nontemporal_load(
          (const uintv4*)&arow[(u * 256 + tid) * 4]);
      if (a.x) bits |= 1u << (u * 4 + 0);
      if (a.y) bits |= 1u << (u * 4 + 1);
      if (a.z) bits |= 1u << (u * 4 + 2);
      if (a.w) bits |= 1u << (u * 4 + 3);
    }
    const int cnt = __popc(bits);
    int v = cnt;
    #pragma unroll
    for (int o = 1; o < 64; o <<= 1) {
      int u = __shfl_up(v, o);
      if (lane >= o) v += u;
    }
    if (lane == 63) wsum[wv] = v;
    __syncthreads();
    int base = 0, total = 0;
    #pragma unroll
    for (int ww = 0; ww < 4; ++ww) {
      int s = wsum[ww];
      if (ww < wv) base += s;
      total += s;
    }
    int off = base + v - cnt;
    #pragma unroll
    for (int u = 0; u < 8; ++u)
      #pragma unroll
      for (int bq = 0; bq < 4; ++bq)
        if (bits & (1u << (u * 4 + bq))) {
          if (off < MAXD) nbr_g[(size_t)i * MAXD + off] = (ushort)((u * 256 + tid) * 4 + bq);
          ++off;
        }
    if (tid == 0) deg_g[i] = min(total, MAXD);
  }
}

// ---------------------------------------------------------------------------
// Kernel 2: panel attention for ONE panel P (temporal blocking: 4 sequential
// launches). Per launch the gather touches a 2 MB Whb stripe -> replicates
// into EVERY XCD's L2 (no placement assumption). CSR loads and out stores are
// NON-TEMPORAL so the stripe stays resident. 4 rows/block, wave-per-row.
// ---------------------------------------------------------------------------
__global__ __launch_bounds__(256) void gat_panel(const ushort* __restrict__ nbr_g,
                                                 const int* __restrict__ deg_g,
                                                 const ushort* __restrict__ Whb,
                                                 const float* __restrict__ f1,
                                                 const float* __restrict__ f2,
                                                 float* __restrict__ out,
                                                 int P) {
  const int w = threadIdx.x >> 6;              // wave -> row slot
  const int i = blockIdx.x * 4 + w;
  const int t = threadIdx.x & 63;

  __shared__ int   nbr[4][MAXD];
  __shared__ float ps[4][MAXD][2];

  const int deg = deg_g[i];
  if (t < deg)
    nbr[w][t] = __builtin_nontemporal_load(&nbr_g[(size_t)i * MAXD + t]);
  if (t + 64 < deg)
    nbr[w][t + 64] = __builtin_nontemporal_load(&nbr_g[(size_t)i * MAXD + t + 64]);
  // wave-private LDS: in-wave program order + lgkmcnt make this safe barrier-free

  const int h = t >> 5;                        // half-wave -> head within panel
  const int l = t & 31;
  const float f1v = f1[(size_t)i * H_N + 2 * P + h];
  float s = 0.f;
  for (int n = l; n < deg; n += 32) {
    const float2 v = *(const float2*)&f2[(size_t)nbr[w][n] * H_N + 2 * P];
    float e = f1v + (h ? v.y : v.x);
    e = e > 0.f ? e : 0.2f * e;                // leaky_relu(0.2)
    e = __expf(e);                             // no max-shift (bounded logits)
    ps[w][n][h] = e;
    s += e;
  }
  #pragma unroll
  for (int o = 16; o; o >>= 1) s += __shfl_xor(s, o);  // stays within 32-half
  const float inv = 1.0f / s;

  // gather/accumulate: lane t owns panel cols {2t, 2t+1}; head = t>>5
  const int colbase = P * 128 + t * 2;
  float a0 = 0.f, a1c = 0.f;
  #pragma unroll 8
  for (int n = 0; n < deg; ++n) {
    const float pv = ps[w][n][h];
    const ushort2 u = *(const ushort2*)&Whb[(size_t)nbr[w][n] * NOUT + colbase];
    a0  += pv * bf2f(u.x);
    a1c += pv * bf2f(u.y);
  }
  f32x2 o2; o2.x = a0 * inv; o2.y = a1c * inv;
  __builtin_nontemporal_store(o2, (f32x2*)&out[(size_t)i * NOUT + colbase]);
}

extern "C" void kernel_launch(void* const* d_in, const int* in_sizes, int n_in,
                              void* d_out, int out_size, void* d_ws, size_t ws_size,
                              hipStream_t stream) {
  const float* x   = (const float*)d_in[0];
  const float* adj = (const float*)d_in[1];
  const float* W   = (const float*)d_in[2];
  const float* a1  = (const float*)d_in[3];
  const float* a2  = (const float*)d_in[4];
  float* out = (float*)d_out;

  ushort* Whb = (ushort*)d_ws;                           // 8 MB
  ushort* xb  = Whb + (size_t)N_NODES * NOUT;            // 8 MB
  ushort* Wt  = xb + (size_t)N_NODES * F_IN;             // 0.5 MB
  float*  f1  = (float*)(Wt + (size_t)H_N * D_O * F_IN);
  float*  f2  = f1 + (size_t)N_NODES * H_N;
  ushort* nbr_g = (ushort*)(f2 + (size_t)N_NODES * H_N); // 2 MB
  int*    deg_g = (int*)(nbr_g + (size_t)N_NODES * MAXD);

  hipLaunchKernelGGL(convert, dim3(2112), dim3(256), 0, stream, x, W, xb, Wt);
  hipLaunchKernelGGL(scan_gemm, dim3(512 + N_NODES), dim3(256), 0, stream,
                     (const uint32_t*)adj, xb, Wt, a1, a2, Whb, f1, f2, nbr_g, deg_g);
  for (int P = 0; P < 4; ++P)
    hipLaunchKernelGGL(gat_panel, dim3(N_NODES / 4), dim3(256), 0, stream,
                       nbr_g, deg_g, Whb, f1, f2, out, P);
}

// Round 21
// 89.747 us; speedup vs baseline: 1.1190x; 1.1190x over previous
//
#include <hip/hip_runtime.h>
#include <hip/hip_bf16.h>
#include <cstdint>

#define N_NODES 8192
#define F_IN    512
#define D_O     64
#define H_N     8
#define NOUT    512   // H_N * D_O
#define MAXD    128   // max supported degree (mean ~33.8, sigma 5.7 -> 16 sigma)

#define BM 64
#define BN 128
#define BK 64

typedef __attribute__((ext_vector_type(8))) short short8;
typedef __attribute__((ext_vector_type(4))) float f32x4;
typedef __attribute__((ext_vector_type(4))) unsigned int uintv4;

static __device__ __forceinline__ ushort f2bf(float f) {
  union { float f; uint32_t u; } v; v.f = f;
  uint32_t r = v.u + 0x7FFFu + ((v.u >> 16) & 1u);  // RNE
  return (ushort)(r >> 16);
}
static __device__ __forceinline__ float bf2f(ushort u) {
  union { uint32_t u; float f; } v; v.u = ((uint32_t)u) << 16;
  return v.f;
}

// ---------------------------------------------------------------------------
// Kernel 0: blocks [0,2048): xb = bf16(x)   (grid-stride float4)
//           blocks [2048,2112): Wt[h][d][k] = bf16(W[h][k][d]) via LDS tile
// ---------------------------------------------------------------------------
__global__ __launch_bounds__(256) void convert(const float* __restrict__ x,
                                               const float* __restrict__ W,
                                               ushort* __restrict__ xb,
                                               ushort* __restrict__ Wt) {
  __shared__ float Ws[64][65];
  const int b = blockIdx.x, t = threadIdx.x;
  if (b < 2048) {
    const int gid = b * 256 + t;
    #pragma unroll
    for (int it = 0; it < 2; ++it) {
      const int q = gid + it * 524288;           // 2*524288 = 1,048,576 float4s
      const float4 v = ((const float4*)x)[q];
      ushort4 u;
      u.x = f2bf(v.x); u.y = f2bf(v.y); u.z = f2bf(v.z); u.w = f2bf(v.w);
      ((ushort4*)xb)[q] = u;
    }
  } else {
    const int bb = b - 2048;                     // 64 blocks = 8 heads x 8 k-tiles
    const int h = bb >> 3, kt = bb & 7;
    const int d = t & 63, krg = (t >> 6) * 16;
    const float* src = &W[((size_t)h * F_IN + kt * 64 + krg) * D_O + d];
    #pragma unroll
    for (int q = 0; q < 16; ++q)
      Ws[krg + q][d] = src[(size_t)q * D_O];     // coalesced over d
    __syncthreads();
    const int d0 = t >> 2, kq = (t & 3) * 16;
    ushort* dst = &Wt[(size_t)h * D_O * F_IN + (size_t)d0 * F_IN + kt * 64 + kq];
    #pragma unroll
    for (int q = 0; q < 16; ++q)
      dst[q] = f2bf(Ws[kq + q][d0]);             // coalesced over k
  }
}

// ---------------------------------------------------------------------------
// Kernel 1 (fused): blocks [0,512): GEMM tiles; blocks [512,8704): adj-row
// scan writing ushort CSR. adj loads are NON-TEMPORAL (nt) so the 256 MB
// stream does not evict Whb/CSR from L3 -> panel gathers stay L3-warm.
// ---------------------------------------------------------------------------
__global__ __launch_bounds__(256) void scan_gemm(const uint32_t* __restrict__ adj,
                                                 const ushort* __restrict__ xb,
                                                 const ushort* __restrict__ Wt,
                                                 const float* __restrict__ a1,
                                                 const float* __restrict__ a2,
                                                 ushort* __restrict__ Whb,
                                                 float* __restrict__ f1,
                                                 float* __restrict__ f2,
                                                 ushort* __restrict__ nbr_g,
                                                 int* __restrict__ deg_g) {
  __shared__ ushort As[BM][BK + 8];
  __shared__ ushort Bs[BN][BK + 8];
  __shared__ int wsum[4];

  const int id   = blockIdx.x;
  const int tid  = threadIdx.x;
  const int lane = tid & 63;
  const int wv   = tid >> 6;

  if (id < 512) {
    // ---------------- GEMM role ----------------
    const int wr = wv >> 1, wc = wv & 1;
    const int r0 = (id >> 2) * BM;
    const int c0 = (id & 3) * BN;
    const int lm = lane & 15;
    const int lg = lane >> 4;

    f32x4 acc[2][4];
    #pragma unroll
    for (int m2 = 0; m2 < 2; ++m2)
      #pragma unroll
      for (int n2 = 0; n2 < 4; ++n2)
        acc[m2][n2] = (f32x4){0.f, 0.f, 0.f, 0.f};

    for (int k0 = 0; k0 < F_IN; k0 += BK) {
      __syncthreads();
      #pragma unroll
      for (int p = 0; p < 2; ++p) {
        const int e = p * 256 + tid;
        const int row = e >> 3, ck = (e & 7) * 8;
        *(short8*)&As[row][ck] = *(const short8*)&xb[(size_t)(r0 + row) * F_IN + k0 + ck];
      }
      #pragma unroll
      for (int p = 0; p < 4; ++p) {
        const int e = p * 256 + tid;
        const int row = e >> 3, ck = (e & 7) * 8;
        *(short8*)&Bs[row][ck] = *(const short8*)&Wt[(size_t)(c0 + row) * F_IN + k0 + ck];
      }
      __syncthreads();

      #pragma unroll
      for (int kk = 0; kk < 2; ++kk) {
        const int koff = kk * 32 + lg * 8;
        short8 af[2], bf[4];
        #pragma unroll
        for (int m2 = 0; m2 < 2; ++m2)
          af[m2] = *(const short8*)&As[wr * 32 + m2 * 16 + lm][koff];
        #pragma unroll
        for (int n2 = 0; n2 < 4; ++n2)
          bf[n2] = *(const short8*)&Bs[wc * 64 + n2 * 16 + lm][koff];
        #pragma unroll
        for (int m2 = 0; m2 < 2; ++m2)
          #pragma unroll
          for (int n2 = 0; n2 < 4; ++n2)
            acc[m2][n2] = __builtin_amdgcn_mfma_f32_16x16x32_bf16(af[m2], bf[n2], acc[m2][n2], 0, 0, 0);
      }
    }

    // epilogue: Whb write + fused f1/f2
    const int head = (c0 >> 6) + wc;
    float a1v[4], a2v[4];
    #pragma unroll
    for (int n2 = 0; n2 < 4; ++n2) {
      a1v[n2] = a1[head * D_O + n2 * 16 + lm];
      a2v[n2] = a2[head * D_O + n2 * 16 + lm];
    }
    #pragma unroll
    for (int m2 = 0; m2 < 2; ++m2) {
      #pragma unroll
      for (int r = 0; r < 4; ++r) {
        const int row = r0 + wr * 32 + m2 * 16 + lg * 4 + r;
        float p1 = 0.f, p2 = 0.f;
        #pragma unroll
        for (int n2 = 0; n2 < 4; ++n2) {
          const float v = acc[m2][n2][r];
          p1 += v * a1v[n2];
          p2 += v * a2v[n2];
          Whb[(size_t)row * NOUT + c0 + wc * 64 + n2 * 16 + lm] = f2bf(v);
        }
        #pragma unroll
        for (int o = 1; o < 16; o <<= 1) {
          p1 += __shfl_xor(p1, o);
          p2 += __shfl_xor(p2, o);
        }
        if (lm == 0) {
          f1[(size_t)row * H_N + head] = p1;
          f2[(size_t)row * H_N + head] = p2;
        }
      }
    }
  } else {
    // ---------------- SCAN role (nt loads) ----------------
    const int i = id - 512;
    const uint32_t* arow = adj + (size_t)i * N_NODES;
    uint32_t bits = 0;
    #pragma unroll
    for (int u = 0; u < 8; ++u) {
      const uintv4 a = __builtin_nontemporal_load(
          (const uintv4*)&arow[(u * 256 + tid) * 4]);
      if (a.x) bits |= 1u << (u * 4 + 0);
      if (a.y) bits |= 1u << (u * 4 + 1);
      if (a.z) bits |= 1u << (u * 4 + 2);
      if (a.w) bits |= 1u << (u * 4 + 3);
    }
    const int cnt = __popc(bits);
    int v = cnt;
    #pragma unroll
    for (int o = 1; o < 64; o <<= 1) {
      int u = __shfl_up(v, o);
      if (lane >= o) v += u;
    }
    if (lane == 63) wsum[wv] = v;
    __syncthreads();
    int base = 0, total = 0;
    #pragma unroll
    for (int ww = 0; ww < 4; ++ww) {
      int s = wsum[ww];
      if (ww < wv) base += s;
      total += s;
    }
    int off = base + v - cnt;
    #pragma unroll
    for (int u = 0; u < 8; ++u)
      #pragma unroll
      for (int bq = 0; bq < 4; ++bq)
        if (bits & (1u << (u * 4 + bq))) {
          if (off < MAXD) nbr_g[(size_t)i * MAXD + off] = (ushort)((u * 256 + tid) * 4 + bq);
          ++off;
        }
    if (tid == 0) deg_g[i] = min(total, MAXD);
  }
}

// ---------------------------------------------------------------------------
// Kernel 2: panel attention, 4 rows/block (wave-per-row, zero barriers),
// XCD-pinned: panel = (bid&7)>>1. i = (bid>>3)*8 + (bid&1)*4 + w (bijective).
// ---------------------------------------------------------------------------
__global__ __launch_bounds__(256) void gat_panel(const ushort* __restrict__ nbr_g,
                                                 const int* __restrict__ deg_g,
                                                 const ushort* __restrict__ Whb,
                                                 const float* __restrict__ f1,
                                                 const float* __restrict__ f2,
                                                 float* __restrict__ out) {
  const int bid = blockIdx.x;
  const int xcd = bid & 7;
  const int P   = xcd >> 1;                    // panel pinned to XCD pair
  const int w   = threadIdx.x >> 6;            // wave -> row slot
  const int i   = (bid >> 3) * 8 + (xcd & 1) * 4 + w;
  const int t   = threadIdx.x & 63;

  __shared__ int   nbr[4][MAXD];
  __shared__ float ps[4][MAXD][2];

  const int deg = deg_g[i];
  if (t < deg)      nbr[w][t]      = nbr_g[(size_t)i * MAXD + t];
  if (t + 64 < deg) nbr[w][t + 64] = nbr_g[(size_t)i * MAXD + t + 64];
  // wave-private LDS: in-wave program order + lgkmcnt make this safe barrier-free

  const int h = t >> 5;                        // half-wave -> head within panel
  const int l = t & 31;
  const float f1v = f1[(size_t)i * H_N + 2 * P + h];
  float s = 0.f;
  for (int n = l; n < deg; n += 32) {
    const float2 v = *(const float2*)&f2[(size_t)nbr[w][n] * H_N + 2 * P];
    float e = f1v + (h ? v.y : v.x);
    e = e > 0.f ? e : 0.2f * e;                // leaky_relu(0.2)
    e = __expf(e);                             // no max-shift (bounded logits)
    ps[w][n][h] = e;
    s += e;
  }
  #pragma unroll
  for (int o = 16; o; o >>= 1) s += __shfl_xor(s, o);  // stays within 32-half
  const float inv = 1.0f / s;

  // gather/accumulate: lane t owns panel cols {2t, 2t+1}; head = t>>5
  const int colbase = P * 128 + t * 2;
  float a0 = 0.f, a1c = 0.f;
  #pragma unroll 8
  for (int n = 0; n < deg; ++n) {
    const float pv = ps[w][n][h];
    const ushort2 u = *(const ushort2*)&Whb[(size_t)nbr[w][n] * NOUT + colbase];
    a0  += pv * bf2f(u.x);
    a1c += pv * bf2f(u.y);
  }
  float2 o2; o2.x = a0 * inv; o2.y = a1c * inv;
  *(float2*)&out[(size_t)i * NOUT + colbase] = o2;
}

extern "C" void kernel_launch(void* const* d_in, const int* in_sizes, int n_in,
                              void* d_out, int out_size, void* d_ws, size_t ws_size,
                              hipStream_t stream) {
  const float* x   = (const float*)d_in[0];
  const float* adj = (const float*)d_in[1];
  const float* W   = (const float*)d_in[2];
  const float* a1  = (const float*)d_in[3];
  const float* a2  = (const float*)d_in[4];
  float* out = (float*)d_out;

  ushort* Whb = (ushort*)d_ws;                           // 8 MB
  ushort* xb  = Whb + (size_t)N_NODES * NOUT;            // 8 MB
  ushort* Wt  = xb + (size_t)N_NODES * F_IN;             // 0.5 MB
  float*  f1  = (float*)(Wt + (size_t)H_N * D_O * F_IN);
  float*  f2  = f1 + (size_t)N_NODES * H_N;
  ushort* nbr_g = (ushort*)(f2 + (size_t)N_NODES * H_N); // 2 MB
  int*    deg_g = (int*)(nbr_g + (size_t)N_NODES * MAXD);

  hipLaunchKernelGGL(convert, dim3(2112), dim3(256), 0, stream, x, W, xb, Wt);
  hipLaunchKernelGGL(scan_gemm, dim3(512 + N_NODES), dim3(256), 0, stream,
                     (const uint32_t*)adj, xb, Wt, a1, a2, Whb, f1, f2, nbr_g, deg_g);
  hipLaunchKernelGGL(gat_panel, dim3(N_NODES), dim3(256), 0, stream,
                     nbr_g, deg_g, Whb, f1, f2, out);
}